// Round 4
// baseline (387.017 us; speedup 1.0000x reference)
//
#include <hip/hip_runtime.h>

// LSTM: B=4096, T=2048, I=1, H=16. 16 lanes/seq, 4 seqs/wave64.
// R2: matvec via v_dot2_f32_f16 (f16 mul, f32 acc), act-scale folding.
// R3: (a) amdgpu_waves_per_eu(1,1) + small live set so weights/x stay in
//     architected VGPRs (R2's VGPR_Count=44 << ~80 live => AGPR churn, the
//     ~130 cyc/step gap between counted issue and measured VALUBusy);
//     (b) pair-rotations via ds_swizzle_b32 (LDS pipe, independent) instead
//     of a serial 10-deep DPP chain: -9 VALU ops/step, shorter dep chain.

constexpr int T_LEN = 2048;

typedef _Float16 h2 __attribute__((ext_vector_type(2)));

template<int CTRL>
__device__ __forceinline__ unsigned dpp_u32(unsigned v) {
  return (unsigned)__builtin_amdgcn_update_dpp(0, (int)v, CTRL, 0xF, 0xF, true);
}
template<int CTRL>
__device__ __forceinline__ float dpp_f32(float v) {
  return __int_as_float(__builtin_amdgcn_update_dpp(
      0, __float_as_int(v), CTRL, 0xF, 0xF, true));
}

__device__ __forceinline__ float fexp2(float x) { return __builtin_amdgcn_exp2f(x); }
__device__ __forceinline__ float frcp(float x)  { return __builtin_amdgcn_rcpf(x); }
__device__ __forceinline__ h2 u2h(unsigned u) { union { unsigned u; h2 h; } c; c.u = u; return c.h; }

// ds_swizzle BitMode: offset = (xor<<10) | (or<<5) | and ; and=0x1F keeps
// lane bits 0-4, xor < 16 stays within each 16-lane group. One LDS-pipe op.
#define SWZ(V, M) ((unsigned)__builtin_amdgcn_ds_swizzle((int)(V), (((M) << 10) | 0x1F)))

// One LSTM timestep. S = step-in-block literal (0..15), XT = x scalar.
#define GSTEP(S, XT) do {                                                  \
    const float xt = (XT);                                                 \
    float a0 = fmaf(xt, wih0, bb0);                                        \
    float a1 = fmaf(xt, wih1, bb1);                                        \
    float a2 = fmaf(xt, wih2, bb2);                                        \
    float a3 = fmaf(xt, wih3, bb3);                                        \
    unsigned hu; { union { _Float16 f; unsigned short s; } cc;             \
      cc.f = (_Float16)h; hu = cc.s; }                                     \
    const unsigned hn = dpp_u32<0xB1>(hu);                                 \
    const unsigned c0 = __builtin_amdgcn_perm(hn, hu, 0x05040100);         \
    const unsigned c1 = SWZ(c0, 2);                                        \
    const unsigned c2 = SWZ(c0, 4);                                        \
    const unsigned c3 = SWZ(c0, 6);                                        \
    const unsigned c4 = SWZ(c0, 8);                                        \
    const unsigned c5 = SWZ(c0, 10);                                       \
    const unsigned c6 = SWZ(c0, 12);                                       \
    const unsigned c7 = SWZ(c0, 14);                                       \
    a0 = __builtin_amdgcn_fdot2(u2h(c0), w0p[0], a0, false);               \
    a1 = __builtin_amdgcn_fdot2(u2h(c0), w1p[0], a1, false);               \
    a2 = __builtin_amdgcn_fdot2(u2h(c0), w2p[0], a2, false);               \
    a3 = __builtin_amdgcn_fdot2(u2h(c0), w3p[0], a3, false);               \
    a0 = __builtin_amdgcn_fdot2(u2h(c1), w0p[1], a0, false);               \
    a1 = __builtin_amdgcn_fdot2(u2h(c1), w1p[1], a1, false);               \
    a2 = __builtin_amdgcn_fdot2(u2h(c1), w2p[1], a2, false);               \
    a3 = __builtin_amdgcn_fdot2(u2h(c1), w3p[1], a3, false);               \
    a0 = __builtin_amdgcn_fdot2(u2h(c2), w0p[2], a0, false);               \
    a1 = __builtin_amdgcn_fdot2(u2h(c2), w1p[2], a1, false);               \
    a2 = __builtin_amdgcn_fdot2(u2h(c2), w2p[2], a2, false);               \
    a3 = __builtin_amdgcn_fdot2(u2h(c2), w3p[2], a3, false);               \
    a0 = __builtin_amdgcn_fdot2(u2h(c3), w0p[3], a0, false);               \
    a1 = __builtin_amdgcn_fdot2(u2h(c3), w1p[3], a1, false);               \
    a2 = __builtin_amdgcn_fdot2(u2h(c3), w2p[3], a2, false);               \
    a3 = __builtin_amdgcn_fdot2(u2h(c3), w3p[3], a3, false);               \
    a0 = __builtin_amdgcn_fdot2(u2h(c4), w0p[4], a0, false);               \
    a1 = __builtin_amdgcn_fdot2(u2h(c4), w1p[4], a1, false);               \
    a2 = __builtin_amdgcn_fdot2(u2h(c4), w2p[4], a2, false);               \
    a3 = __builtin_amdgcn_fdot2(u2h(c4), w3p[4], a3, false);               \
    a0 = __builtin_amdgcn_fdot2(u2h(c5), w0p[5], a0, false);               \
    a1 = __builtin_amdgcn_fdot2(u2h(c5), w1p[5], a1, false);               \
    a2 = __builtin_amdgcn_fdot2(u2h(c5), w2p[5], a2, false);               \
    a3 = __builtin_amdgcn_fdot2(u2h(c5), w3p[5], a3, false);               \
    a0 = __builtin_amdgcn_fdot2(u2h(c6), w0p[6], a0, false);               \
    a1 = __builtin_amdgcn_fdot2(u2h(c6), w1p[6], a1, false);               \
    a2 = __builtin_amdgcn_fdot2(u2h(c6), w2p[6], a2, false);               \
    a3 = __builtin_amdgcn_fdot2(u2h(c6), w3p[6], a3, false);               \
    a0 = __builtin_amdgcn_fdot2(u2h(c7), w0p[7], a0, false);               \
    a1 = __builtin_amdgcn_fdot2(u2h(c7), w1p[7], a1, false);               \
    a2 = __builtin_amdgcn_fdot2(u2h(c7), w2p[7], a2, false);               \
    a3 = __builtin_amdgcn_fdot2(u2h(c7), w3p[7], a3, false);               \
    const float iv = frcp(1.0f + fexp2(a0));                               \
    const float fv = frcp(1.0f + fexp2(a1));                               \
    const float gv = fmaf(frcp(1.0f + fexp2(a2)), 2.0f, -1.0f);            \
    const float ov = frcp(1.0f + fexp2(a3));                               \
    c = fmaf(fv, c, iv * gv);                                              \
    const float th = fmaf(frcp(1.0f + fexp2(c * KG)), 2.0f, -1.0f);        \
    h = ov * th;                                                           \
    float p_ = h * wfcj;                                                   \
    p_ += dpp_f32<0xB1>(p_);                                               \
    p_ += dpp_f32<0x4E>(p_);                                               \
    p_ += dpp_f32<0x141>(p_);                                              \
    p_ += dpp_f32<0x140>(p_);                                              \
    ykeep = (j == (S)) ? (p_ + bfc) : ykeep;                               \
  } while (0)

// 16 steps: consumes float4s QA..QD (x for t..t+15), prefetches next body's
// x into NA..ND, stores this block's y.
#define BODY(QA, QB, QC, QD, NA, NB_, NC, ND, BLK) do {                    \
    const int nb = ((BLK) + 1) & (NBLK - 1);                               \
    NA = xq[nb * 4 + 0];                                                   \
    NB_ = xq[nb * 4 + 1];                                                  \
    NC = xq[nb * 4 + 2];                                                   \
    ND = xq[nb * 4 + 3];                                                   \
    GSTEP(0,  QA.x); GSTEP(1,  QA.y); GSTEP(2,  QA.z); GSTEP(3,  QA.w);    \
    GSTEP(4,  QB.x); GSTEP(5,  QB.y); GSTEP(6,  QB.z); GSTEP(7,  QB.w);    \
    GSTEP(8,  QC.x); GSTEP(9,  QC.y); GSTEP(10, QC.z); GSTEP(11, QC.w);    \
    GSTEP(12, QD.x); GSTEP(13, QD.y); GSTEP(14, QD.z); GSTEP(15, QD.w);    \
    yb[(BLK) * 16 + j] = ykeep;                                            \
  } while (0)

__global__ __launch_bounds__(256)
__attribute__((amdgpu_waves_per_eu(1, 1)))
void lstm_fused_kernel(
    const float* __restrict__ x, const float* __restrict__ W_ih,
    const float* __restrict__ W_hh, const float* __restrict__ b_ih,
    const float* __restrict__ b_hh, const float* __restrict__ W_fc,
    const float* __restrict__ b_fc, float* __restrict__ out)
{
  const int tid  = blockIdx.x * blockDim.x + threadIdx.x;
  const int wave = tid >> 6;
  const int lane = tid & 63;
  const int grp  = (lane >> 4) & 3;
  const int j    = lane & 15;
  const int b    = wave * 4 + grp;

  const float4* __restrict__ xq = reinterpret_cast<const float4*>(x + (size_t)b * T_LEN);
  float*        __restrict__ yb = out + (size_t)b * T_LEN;

  const int r0 = j, r1 = j + 16, r2 = j + 32, r3 = j + 48;

  // Fold activation arg scale into weights: sigmoid rows (i,f,o) * -log2e,
  // tanh rows (g) * -2log2e, so each act is rcp(1+exp2(a)).
  constexpr float KN = -1.4426950408889634f;
  constexpr float KG = -2.8853900817779268f;
  const float s0 = KN, s1 = KN, s2 = KG, s3 = KN;

  // Pre-gathered, xor-permuted, pre-scaled f16 weight pairs:
  // wXp[p] = { W[r][j^2p]*s, W[r][j^(2p)^1]*s }
  h2 w0p[8], w1p[8], w2p[8], w3p[8];
#pragma unroll
  for (int p = 0; p < 8; ++p) {
    const int ka = j ^ (2 * p), kb = (j ^ (2 * p)) ^ 1;
    w0p[p] = h2{(_Float16)(W_hh[r0 * 16 + ka] * s0), (_Float16)(W_hh[r0 * 16 + kb] * s0)};
    w1p[p] = h2{(_Float16)(W_hh[r1 * 16 + ka] * s1), (_Float16)(W_hh[r1 * 16 + kb] * s1)};
    w2p[p] = h2{(_Float16)(W_hh[r2 * 16 + ka] * s2), (_Float16)(W_hh[r2 * 16 + kb] * s2)};
    w3p[p] = h2{(_Float16)(W_hh[r3 * 16 + ka] * s3), (_Float16)(W_hh[r3 * 16 + kb] * s3)};
  }
  const float wih0 = W_ih[r0] * s0, wih1 = W_ih[r1] * s1;
  const float wih2 = W_ih[r2] * s2, wih3 = W_ih[r3] * s3;
  const float bb0 = (b_ih[r0] + b_hh[r0]) * s0;
  const float bb1 = (b_ih[r1] + b_hh[r1]) * s1;
  const float bb2 = (b_ih[r2] + b_hh[r2]) * s2;
  const float bb3 = (b_ih[r3] + b_hh[r3]) * s3;
  const float wfcj = W_fc[j];
  const float bfc  = b_fc[0];

  float h = 0.0f, c = 0.0f, ykeep = 0.0f;

  constexpr int NBLK = T_LEN / 16;  // 128 blocks of 16 steps

  float4 qa = xq[0], qb = xq[1], qc = xq[2], qd = xq[3];
  float4 na, nbv, nc, nd;

  for (int it = 0; it < NBLK / 2; ++it) {
    BODY(qa, qb, qc, qd, na, nbv, nc, nd, 2 * it);
    BODY(na, nbv, nc, nd, qa, qb, qc, qd, 2 * it + 1);
  }
}

extern "C" void kernel_launch(void* const* d_in, const int* in_sizes, int n_in,
                              void* d_out, int out_size, void* d_ws, size_t ws_size,
                              hipStream_t stream) {
  const float* x    = (const float*)d_in[0];
  const float* W_ih = (const float*)d_in[1];
  const float* W_hh = (const float*)d_in[2];
  const float* b_ih = (const float*)d_in[3];
  const float* b_hh = (const float*)d_in[4];
  const float* W_fc = (const float*)d_in[5];
  const float* b_fc = (const float*)d_in[6];
  float* out = (float*)d_out;

  dim3 grid(256), block(256);
  hipLaunchKernelGGL(lstm_fused_kernel, grid, block, 0, stream,
                     x, W_ih, W_hh, b_ih, b_hh, W_fc, b_fc, out);
}

// Round 6
// 329.616 us; speedup vs baseline: 1.1741x; 1.1741x over previous
//
#include <hip/hip_runtime.h>

// LSTM: B=4096, T=2048, I=1, H=16. 16 lanes/seq, 4 seqs/wave64, 1024 waves.
// R2: matvec via v_dot2_f32_f16 (f16 mul, f32 acc), act-scale folding.
// R3 lesson: ds_swizzle rotations put LDS latency on the critical path at
//   1 wave/SIMD -> revert to pure-DPP rotation chain (VALU pipe). Keep
//   waves_per_eu(1,1): VGPR 44->132 killed the accvgpr weight churn.
// R4: (a) rcp-merged activations: c' = [c*pi*pg + (1-eg)*pf]/(pf*pi*pg),
//     h = (1-ec)/(pc*po) -> 5 exp2 + 2 rcp (was 5+5). c clamped to +-32
//     (tanh saturates) to avoid inf*0 NaN in the merged form.
//     (b) h-pair pack via v_cvt_pkrtz_f16_f32 (2 instrs, was 3).
//     (c) +b_fc folded into the once-per-16-step store.
// R5: fix cvt_pkrtz return-type mismatch (bit_cast, no behavior change).

constexpr int T_LEN = 2048;

typedef _Float16 h2 __attribute__((ext_vector_type(2)));

template<int CTRL>
__device__ __forceinline__ unsigned dpp_u32(unsigned v) {
  return (unsigned)__builtin_amdgcn_update_dpp(0, (int)v, CTRL, 0xF, 0xF, true);
}
template<int CTRL>
__device__ __forceinline__ float dpp_f32(float v) {
  return __int_as_float(__builtin_amdgcn_update_dpp(
      0, __float_as_int(v), CTRL, 0xF, 0xF, true));
}

__device__ __forceinline__ float fexp2(float x) { return __builtin_amdgcn_exp2f(x); }
__device__ __forceinline__ float frcp(float x)  { return __builtin_amdgcn_rcpf(x); }
__device__ __forceinline__ h2 u2h(unsigned u) { union { unsigned u; h2 h; } c; c.u = u; return c.h; }

// cvt_pkrtz returns __fp16x2; bit-cast to u32 regardless of element type.
__device__ __forceinline__ unsigned pkrtz_u32(float lo, float hi) {
  return __builtin_bit_cast(unsigned, __builtin_amdgcn_cvt_pkrtz(lo, hi));
}

// DPP ctrl: 0xB1=^1  0x4E=^2  0x1B=^3  0x141=^7(row_half_mirror)  0x140=^15(row_mirror)

#define DOT4(CU, P) do {                                                   \
    a0 = __builtin_amdgcn_fdot2(u2h(CU), w0p[P], a0, false);               \
    a1 = __builtin_amdgcn_fdot2(u2h(CU), w1p[P], a1, false);               \
    a2 = __builtin_amdgcn_fdot2(u2h(CU), w2p[P], a2, false);               \
    a3 = __builtin_amdgcn_fdot2(u2h(CU), w3p[P], a3, false);               \
  } while (0)

// One LSTM timestep. S = step-in-block literal (0..15), XT = x scalar.
#define GSTEP(S, XT) do {                                                  \
    const float xt = (XT);                                                 \
    float a0 = fmaf(xt, wih0, bb0);                                        \
    float a1 = fmaf(xt, wih1, bb1);                                        \
    float a2 = fmaf(xt, wih2, bb2);                                        \
    float a3 = fmaf(xt, wih3, bb3);                                        \
    const float hn = dpp_f32<0xB1>(h);                                     \
    unsigned cur = pkrtz_u32(h, hn);                                       \
    DOT4(cur, 0);                                                          \
    cur = dpp_u32<0x4E>(cur);                            DOT4(cur, 1);     \
    cur = dpp_u32<0x141>(cur); cur = dpp_u32<0xB1>(cur); DOT4(cur, 2);     \
    cur = dpp_u32<0x4E>(cur);                            DOT4(cur, 3);     \
    cur = dpp_u32<0x140>(cur); cur = dpp_u32<0xB1>(cur); DOT4(cur, 4);     \
    cur = dpp_u32<0x4E>(cur);                            DOT4(cur, 5);     \
    cur = dpp_u32<0x141>(cur); cur = dpp_u32<0xB1>(cur); DOT4(cur, 6);     \
    cur = dpp_u32<0x4E>(cur);                            DOT4(cur, 7);     \
    const float e0 = fexp2(a0);                                            \
    const float e1 = fexp2(a1);                                            \
    const float e2 = fexp2(a2);                                            \
    const float e3 = fexp2(a3);                                            \
    const float pi_ = 1.0f + e0;                                           \
    const float pf_ = 1.0f + e1;                                           \
    const float pg_ = 1.0f + e2;                                           \
    const float po_ = 1.0f + e3;                                           \
    const float pig = pi_ * pg_;                                           \
    const float den = pf_ * pig;                                           \
    const float tg  = (1.0f - e2) * pf_;                                   \
    const float num = fmaf(c, pig, tg);                                    \
    c = num * frcp(den);                                                   \
    c = fminf(fmaxf(c, -32.0f), 32.0f);                                    \
    const float ec = fexp2(c * KG);                                        \
    const float pc_ = 1.0f + ec;                                           \
    h = (1.0f - ec) * frcp(pc_ * po_);                                     \
    float p_ = h * wfcj;                                                   \
    p_ += dpp_f32<0xB1>(p_);                                               \
    p_ += dpp_f32<0x4E>(p_);                                               \
    p_ += dpp_f32<0x141>(p_);                                              \
    p_ += dpp_f32<0x140>(p_);                                              \
    ykeep = (j == (S)) ? p_ : ykeep;                                       \
  } while (0)

// 16 steps: consumes float4s QA..QD (x for t..t+15), prefetches next body's
// x into NA..ND, stores this block's y (+ b_fc folded here).
#define BODY(QA, QB, QC, QD, NA, NB_, NC, ND, BLK) do {                    \
    const int nb = ((BLK) + 1) & (NBLK - 1);                               \
    NA  = xq[nb * 4 + 0];                                                  \
    NB_ = xq[nb * 4 + 1];                                                  \
    NC  = xq[nb * 4 + 2];                                                  \
    ND  = xq[nb * 4 + 3];                                                  \
    GSTEP(0,  QA.x); GSTEP(1,  QA.y); GSTEP(2,  QA.z); GSTEP(3,  QA.w);    \
    GSTEP(4,  QB.x); GSTEP(5,  QB.y); GSTEP(6,  QB.z); GSTEP(7,  QB.w);    \
    GSTEP(8,  QC.x); GSTEP(9,  QC.y); GSTEP(10, QC.z); GSTEP(11, QC.w);    \
    GSTEP(12, QD.x); GSTEP(13, QD.y); GSTEP(14, QD.z); GSTEP(15, QD.w);    \
    yb[(BLK) * 16 + j] = ykeep + bfc;                                      \
  } while (0)

__global__ __launch_bounds__(256)
__attribute__((amdgpu_waves_per_eu(1, 1)))
void lstm_fused_kernel(
    const float* __restrict__ x, const float* __restrict__ W_ih,
    const float* __restrict__ W_hh, const float* __restrict__ b_ih,
    const float* __restrict__ b_hh, const float* __restrict__ W_fc,
    const float* __restrict__ b_fc, float* __restrict__ out)
{
  const int tid  = blockIdx.x * blockDim.x + threadIdx.x;
  const int wave = tid >> 6;
  const int lane = tid & 63;
  const int grp  = (lane >> 4) & 3;
  const int j    = lane & 15;
  const int b    = wave * 4 + grp;

  const float4* __restrict__ xq = reinterpret_cast<const float4*>(x + (size_t)b * T_LEN);
  float*        __restrict__ yb = out + (size_t)b * T_LEN;

  const int r0 = j, r1 = j + 16, r2 = j + 32, r3 = j + 48;

  // Fold activation arg scale into weights: sigmoid rows (i,f,o) * -log2e,
  // tanh rows (g) * -2log2e, so e_X = exp2(a_X) = exp(-raw) / exp(-2raw_g).
  constexpr float KN = -1.4426950408889634f;
  constexpr float KG = -2.8853900817779268f;
  const float s0 = KN, s1 = KN, s2 = KG, s3 = KN;

  // Pre-gathered, xor-permuted, pre-scaled f16 weight pairs:
  // wXp[p] = { W[r][j^2p]*s, W[r][j^(2p)^1]*s }
  h2 w0p[8], w1p[8], w2p[8], w3p[8];
#pragma unroll
  for (int p = 0; p < 8; ++p) {
    const int ka = j ^ (2 * p), kb = (j ^ (2 * p)) ^ 1;
    w0p[p] = h2{(_Float16)(W_hh[r0 * 16 + ka] * s0), (_Float16)(W_hh[r0 * 16 + kb] * s0)};
    w1p[p] = h2{(_Float16)(W_hh[r1 * 16 + ka] * s1), (_Float16)(W_hh[r1 * 16 + kb] * s1)};
    w2p[p] = h2{(_Float16)(W_hh[r2 * 16 + ka] * s2), (_Float16)(W_hh[r2 * 16 + kb] * s2)};
    w3p[p] = h2{(_Float16)(W_hh[r3 * 16 + ka] * s3), (_Float16)(W_hh[r3 * 16 + kb] * s3)};
  }
  const float wih0 = W_ih[r0] * s0, wih1 = W_ih[r1] * s1;
  const float wih2 = W_ih[r2] * s2, wih3 = W_ih[r3] * s3;
  const float bb0 = (b_ih[r0] + b_hh[r0]) * s0;
  const float bb1 = (b_ih[r1] + b_hh[r1]) * s1;
  const float bb2 = (b_ih[r2] + b_hh[r2]) * s2;
  const float bb3 = (b_ih[r3] + b_hh[r3]) * s3;
  const float wfcj = W_fc[j];
  const float bfc  = b_fc[0];

  float h = 0.0f, c = 0.0f, ykeep = 0.0f;

  constexpr int NBLK = T_LEN / 16;  // 128 blocks of 16 steps

  float4 qa = xq[0], qb = xq[1], qc = xq[2], qd = xq[3];
  float4 na, nbv, nc, nd;

  for (int it = 0; it < NBLK / 2; ++it) {
    BODY(qa, qb, qc, qd, na, nbv, nc, nd, 2 * it);
    BODY(na, nbv, nc, nd, qa, qb, qc, qd, 2 * it + 1);
  }
}

extern "C" void kernel_launch(void* const* d_in, const int* in_sizes, int n_in,
                              void* d_out, int out_size, void* d_ws, size_t ws_size,
                              hipStream_t stream) {
  const float* x    = (const float*)d_in[0];
  const float* W_ih = (const float*)d_in[1];
  const float* W_hh = (const float*)d_in[2];
  const float* b_ih = (const float*)d_in[3];
  const float* b_hh = (const float*)d_in[4];
  const float* W_fc = (const float*)d_in[5];
  const float* b_fc = (const float*)d_in[6];
  float* out = (float*)d_out;

  dim3 grid(256), block(256);
  hipLaunchKernelGGL(lstm_fused_kernel, grid, block, 0, stream,
                     x, W_ih, W_hh, b_ih, b_hh, W_fc, b_fc, out);
}